// Round 7
// baseline (84.650 us; speedup 1.0000x reference)
//
#include <hip/hip_runtime.h>
#include <hip/hip_bf16.h>
#include <stdint.h>

#define NDIM 128
#define LDK 136      // padded K stride (shorts) for Wt rows
#define BSH 9        // bucket shift: 512 nodes per bucket
#define NB_A 1024    // bucketing grid
#define BCAP 9216    // per-bucket staging capacity (expected ~6400)

typedef __attribute__((ext_vector_type(8))) short bf16x8;
typedef __attribute__((ext_vector_type(4))) float f32x4;

__device__ __forceinline__ unsigned short f2bf(float f) {
    unsigned u = __float_as_uint(f);
    unsigned r = u + 0x7fffu + ((u >> 16) & 1u);   // round-to-nearest-even
    return (unsigned short)(r >> 16);
}
__device__ __forceinline__ float bf2f(unsigned short s) {
    return __uint_as_float(((unsigned)s) << 16);
}

// -------- edge accessor handling int64 vs int32 raw layout ------------------
__device__ __forceinline__ void load_edge(const unsigned* __restrict__ w, int is64, int E,
                                          int e, int& s, int& d) {
    if (is64) {
        s = (int)w[(size_t)2 * e];
        d = (int)w[(size_t)2 * E + (size_t)2 * e];
    } else {
        s = (int)w[e];
        d = (int)w[(size_t)E + e];
    }
}

// -------- detect int64 vs int32 edge buffer: int64 => all odd words zero ----
__global__ void detect_kernel(const unsigned* __restrict__ w, int* flag) {
    __shared__ int any_nonzero;
    if (threadIdx.x == 0) any_nonzero = 0;
    __syncthreads();
    int nz = 0;
    for (int k = threadIdx.x; k < 2048; k += 256) {
        if (w[2 * k + 1] != 0u) nz = 1;
    }
    if (nz) atomicOr(&any_nonzero, 1);
    __syncthreads();
    if (threadIdx.x == 0) *flag = any_nonzero ? 0 : 1;   // 1 = int64 layout
}

// -------- per-block bucket histogram (LDS privatized) -----------------------
__global__ __launch_bounds__(256) void hist_kernel(const unsigned* __restrict__ w,
                                                   const int* __restrict__ flag,
                                                   int* __restrict__ hist,
                                                   int E, int nbuck, int chunk) {
    __shared__ int h[128];
    int t = threadIdx.x;
    if (t < 128) h[t] = 0;
    __syncthreads();
    int is64 = *flag;
    int lo = blockIdx.x * chunk;
    int hi = lo + chunk; if (hi > E) hi = E;
    for (int e = lo + t; e < hi; e += 256) {
        int s, d; load_edge(w, is64, E, e, s, d);
        atomicAdd(&h[d >> BSH], 1);
    }
    __syncthreads();
    if (t < nbuck) hist[(size_t)t * gridDim.x + blockIdx.x] = h[t];
}

// -------- scan of each bucket's 1024 block-counts (one block per bucket) ----
__global__ __launch_bounds__(1024) void scanhist_kernel(int* __restrict__ hist,
                                                        int* __restrict__ btot, int NB) {
    __shared__ int s[1024];
    int t = threadIdx.x;
    size_t base = (size_t)blockIdx.x * NB;
    int v = hist[base + t];
    s[t] = v;
    __syncthreads();
    for (int d = 1; d < 1024; d <<= 1) {
        int add = (t >= d) ? s[t - d] : 0;
        __syncthreads();
        s[t] += add;
        __syncthreads();
    }
    hist[base + t] = s[t] - v;            // exclusive within bucket
    if (t == 1023) btot[blockIdx.x] = s[1023];
}

// -------- scan of bucket totals + off[N] = E --------------------------------
__global__ __launch_bounds__(128) void scanbuck_kernel(const int* __restrict__ btot,
                                                       int* __restrict__ bbase, int nbuck,
                                                       int* __restrict__ off, int N, int E) {
    __shared__ int s[128];
    int t = threadIdx.x;
    int v = (t < nbuck) ? btot[t] : 0;
    s[t] = v;
    __syncthreads();
    for (int d = 1; d < 128; d <<= 1) {
        int add = (t >= d) ? s[t - d] : 0;
        __syncthreads();
        s[t] += add;
        __syncthreads();
    }
    if (t < nbuck) bbase[t] = s[t] - v;   // exclusive
    if (t == 0) off[N] = E;
}

// -------- bucket scatter: packed (src<<9 | local) into reserved runs --------
__global__ __launch_bounds__(256) void bucket_kernel(const unsigned* __restrict__ w,
                                                     const int* __restrict__ flag,
                                                     const int* __restrict__ hist,
                                                     const int* __restrict__ bbase,
                                                     unsigned* __restrict__ ebuf,
                                                     int E, int nbuck, int chunk) {
    __shared__ int cur[128];
    int t = threadIdx.x;
    if (t < nbuck) cur[t] = bbase[t] + hist[(size_t)t * gridDim.x + blockIdx.x];
    __syncthreads();
    int is64 = *flag;
    int lo = blockIdx.x * chunk;
    int hi = lo + chunk; if (hi > E) hi = E;
    for (int e = lo + t; e < hi; e += 256) {
        int s, d; load_edge(w, is64, E, e, s, d);
        int b = d >> BSH;
        int p = atomicAdd(&cur[b], 1);    // LDS atomic
        ebuf[p] = ((unsigned)s << BSH) | (unsigned)(d & ((1 << BSH) - 1));
    }
}

// -------- per-bucket CSR build: cnt/dis/off/adj, all coalesced --------------
__global__ __launch_bounds__(512) void csr_kernel(const unsigned* __restrict__ ebuf,
                                                  const int* __restrict__ bbase,
                                                  const int* __restrict__ btot,
                                                  int* __restrict__ adj,
                                                  int* __restrict__ off,
                                                  float* __restrict__ dis,
                                                  int N) {
    __shared__ int lcnt[512];
    __shared__ int lscan[512];
    __shared__ int cur[512];
    __shared__ int tile[BCAP];
    int b = blockIdx.x, t = threadIdx.x;
    int start = bbase[b], cnt = btot[b];
    lcnt[t] = 0;
    __syncthreads();
    for (int i = t; i < cnt; i += 512) atomicAdd(&lcnt[ebuf[start + i] & 511], 1);
    __syncthreads();
    int v = lcnt[t];
    lscan[t] = v;
    __syncthreads();
    for (int d = 1; d < 512; d <<= 1) {
        int add = (t >= d) ? lscan[t - d] : 0;
        __syncthreads();
        lscan[t] += add;
        __syncthreads();
    }
    int ex = lscan[t] - v;                 // exclusive
    int node = (b << BSH) + t;
    if (node < N) {
        off[node] = start + ex;
        dis[node] = rsqrtf((float)(v + 1));
    }
    cur[t] = ex;
    __syncthreads();
    if (cnt <= BCAP) {
        for (int i = t; i < cnt; i += 512) {
            unsigned wo = ebuf[start + i];
            int p = atomicAdd(&cur[wo & 511], 1);
            tile[p] = (int)(wo >> BSH);
        }
        __syncthreads();
        for (int i = t; i < cnt; i += 512) adj[start + i] = tile[i];
    } else {                               // overflow fallback (never for this input)
        for (int i = t; i < cnt; i += 512) {
            unsigned wo = ebuf[start + i];
            int p = atomicAdd(&cur[wo & 511], 1);
            adj[start + p] = (int)(wo >> BSH);
        }
    }
}

// -------- h' = (x @ W) * dis[row], bf16, persistent blocks ------------------
__global__ __launch_bounds__(256) void gemm_kernel(const float* __restrict__ x,
                                                   const float* __restrict__ W,
                                                   const float* __restrict__ dis,
                                                   unsigned short* __restrict__ hp,
                                                   int N, int ntiles) {
    __shared__ unsigned short Wt[NDIM][LDK];   // Wt[c][k] = bf16(W[k][c])
    int tid = threadIdx.x;
    for (int i = tid; i < NDIM * NDIM; i += 256) {
        int k = i >> 7, c = i & 127;
        Wt[c][k] = f2bf(W[i]);
    }
    __syncthreads();

    const int lane = tid & 63;
    const int wv = tid >> 6;
    const int l15 = lane & 15;
    const int kg = lane >> 4;          // 0..3

    for (int tile = blockIdx.x; tile < ntiles; tile += gridDim.x) {
        const int rowbase = tile * 64 + wv * 16;
        const int arow = rowbase + l15;

        bf16x8 a[4];
#pragma unroll
        for (int s = 0; s < 4; ++s) {
            bf16x8 tt;
            if (arow < N) {
                const float* p = x + (size_t)arow * NDIM + s * 32 + kg * 8;
                float4 f0 = *(const float4*)p;
                float4 f1 = *(const float4*)(p + 4);
                tt[0] = (short)f2bf(f0.x); tt[1] = (short)f2bf(f0.y);
                tt[2] = (short)f2bf(f0.z); tt[3] = (short)f2bf(f0.w);
                tt[4] = (short)f2bf(f1.x); tt[5] = (short)f2bf(f1.y);
                tt[6] = (short)f2bf(f1.z); tt[7] = (short)f2bf(f1.w);
            } else {
#pragma unroll
                for (int e = 0; e < 8; ++e) tt[e] = 0;
            }
            a[s] = tt;
        }

        f32x4 acc[8];
#pragma unroll
        for (int ct = 0; ct < 8; ++ct) acc[ct] = (f32x4){0.f, 0.f, 0.f, 0.f};

#pragma unroll
        for (int ct = 0; ct < 8; ++ct) {
#pragma unroll
            for (int s = 0; s < 4; ++s) {
                bf16x8 bb = *(const bf16x8*)&Wt[ct * 16 + l15][s * 32 + kg * 8];
                acc[ct] = __builtin_amdgcn_mfma_f32_16x16x32_bf16(a[s], bb, acc[ct], 0, 0, 0);
            }
        }

        const int r0 = rowbase + kg * 4;
        float dv[4];
#pragma unroll
        for (int j = 0; j < 4; ++j) dv[j] = (r0 + j < N) ? dis[r0 + j] : 0.f;
#pragma unroll
        for (int ct = 0; ct < 8; ++ct) {
            int col = ct * 16 + l15;
#pragma unroll
            for (int j = 0; j < 4; ++j) {
                int r = r0 + j;
                if (r < N) hp[(size_t)r * NDIM + col] = f2bf(acc[ct][j] * dv[j]);
            }
        }
    }
}

// -------- JAX partitionable threefry bits, counter (0, ctr), key (0, 42) ----
__device__ __forceinline__ unsigned rotl32(unsigned v, int d) {
    return (v << d) | (v >> (32 - d));
}
__device__ __forceinline__ unsigned tf_bits(unsigned ctr) {
    unsigned x0 = 0u, x1 = ctr;
    const unsigned ks0 = 0u, ks1 = 42u, ks2 = 0u ^ 42u ^ 0x1BD11BDAu;
    x0 += ks0; x1 += ks1;
#define RND(r) { x0 += x1; x1 = rotl32(x1, (r)); x1 ^= x0; }
    RND(13) RND(15) RND(26) RND(6)   x0 += ks1; x1 += ks2 + 1u;
    RND(17) RND(29) RND(16) RND(24)  x0 += ks2; x1 += ks0 + 2u;
    RND(13) RND(15) RND(26) RND(6)   x0 += ks0; x1 += ks1 + 3u;
    RND(17) RND(29) RND(16) RND(24)  x0 += ks1; x1 += ks2 + 4u;
    RND(13) RND(15) RND(26) RND(6)   x0 += ks2; x1 += ks0 + 5u;
#undef RND
    return x0 ^ x1;
}

// -------- gather + finalize: 2 nodes per wave, 32 lanes x 4 cols each -------
__global__ __launch_bounds__(256) void gather_kernel(const unsigned short* __restrict__ hp,
                                                     const float* __restrict__ x,
                                                     const int* __restrict__ off,
                                                     const int* __restrict__ adj,
                                                     const float* __restrict__ dis,
                                                     const float* __restrict__ b,
                                                     float* __restrict__ out, int N) {
    int wid = (int)((blockIdx.x * 256u + threadIdx.x) >> 6);
    int lane = threadIdx.x & 63;
    int half = lane >> 5;              // which node of the pair
    int l32 = lane & 31;
    int node = wid * 2 + half;
    bool valid = node < N;
    int nodec = valid ? node : N - 1;
    const float dn = dis[nodec];
    const int c0 = l32 * 4;            // 4 bf16 columns per lane
    const unsigned short* hpc = hp + c0;

    // dropout bits (independent of gather — hoisted to overlap load latency)
    unsigned ctr = (unsigned)(nodec * NDIM + c0);
    unsigned bt0 = tf_bits(ctr);
    unsigned bt1 = tf_bits(ctr + 1u);
    unsigned bt2 = tf_bits(ctr + 2u);
    unsigned bt3 = tf_bits(ctr + 3u);

    // self-loop: h'[node] (already contains dis[node])
    uint2 hv = *(const uint2*)(hpc + (size_t)nodec * NDIM);
    float a00 = bf2f((unsigned short)hv.x), a01 = bf2f((unsigned short)(hv.x >> 16));
    float a02 = bf2f((unsigned short)hv.y), a03 = bf2f((unsigned short)(hv.y >> 16));
    float a10 = 0.f, a11 = 0.f, a12 = 0.f, a13 = 0.f;
    float a20 = 0.f, a21 = 0.f, a22 = 0.f, a23 = 0.f;
    float a30 = 0.f, a31 = 0.f, a32 = 0.f, a33 = 0.f;

    int k0 = valid ? off[nodec] : 0;
    int k1 = valid ? off[nodec + 1] : 0;
    int kb = k0;
    const int sbase = half << 5;
    while (kb < k1) {
        int nb = k1 - kb; if (nb > 32) nb = 32;
        int myadj = (kb + l32 < k1) ? adj[kb + l32] : 0;
        int j = 0;
        for (; j + 4 <= nb; j += 4) {
            int s0 = __shfl(myadj, sbase + j);
            int s1 = __shfl(myadj, sbase + j + 1);
            int s2 = __shfl(myadj, sbase + j + 2);
            int s3 = __shfl(myadj, sbase + j + 3);
            uint2 v0 = *(const uint2*)(hpc + (size_t)s0 * NDIM);
            uint2 v1 = *(const uint2*)(hpc + (size_t)s1 * NDIM);
            uint2 v2 = *(const uint2*)(hpc + (size_t)s2 * NDIM);
            uint2 v3 = *(const uint2*)(hpc + (size_t)s3 * NDIM);
            a00 += bf2f((unsigned short)v0.x); a01 += bf2f((unsigned short)(v0.x >> 16));
            a02 += bf2f((unsigned short)v0.y); a03 += bf2f((unsigned short)(v0.y >> 16));
            a10 += bf2f((unsigned short)v1.x); a11 += bf2f((unsigned short)(v1.x >> 16));
            a12 += bf2f((unsigned short)v1.y); a13 += bf2f((unsigned short)(v1.y >> 16));
            a20 += bf2f((unsigned short)v2.x); a21 += bf2f((unsigned short)(v2.x >> 16));
            a22 += bf2f((unsigned short)v2.y); a23 += bf2f((unsigned short)(v2.y >> 16));
            a30 += bf2f((unsigned short)v3.x); a31 += bf2f((unsigned short)(v3.x >> 16));
            a32 += bf2f((unsigned short)v3.y); a33 += bf2f((unsigned short)(v3.y >> 16));
        }
        for (; j < nb; ++j) {
            int s = __shfl(myadj, sbase + j);
            uint2 v = *(const uint2*)(hpc + (size_t)s * NDIM);
            a00 += bf2f((unsigned short)v.x); a01 += bf2f((unsigned short)(v.x >> 16));
            a02 += bf2f((unsigned short)v.y); a03 += bf2f((unsigned short)(v.y >> 16));
        }
        kb += nb;
    }

    float c0s = (a00 + a10) + (a20 + a30);
    float c1s = (a01 + a11) + (a21 + a31);
    float c2s = (a02 + a12) + (a22 + a32);
    float c3s = (a03 + a13) + (a23 + a33);

    float4 bb = *(const float4*)(b + c0);
    float v0 = fmaxf(fmaf(dn, c0s, bb.x), 0.f);
    float v1 = fmaxf(fmaf(dn, c1s, bb.y), 0.f);
    float v2 = fmaxf(fmaf(dn, c2s, bb.z), 0.f);
    float v3 = fmaxf(fmaf(dn, c3s, bb.w), 0.f);

    v0 = (bt0 >> 31) ? 0.f : v0 * 2.f;
    v1 = (bt1 >> 31) ? 0.f : v1 * 2.f;
    v2 = (bt2 >> 31) ? 0.f : v2 * 2.f;
    v3 = (bt3 >> 31) ? 0.f : v3 * 2.f;

    if (valid) {
        float4 xr = *(const float4*)(x + (size_t)node * NDIM + c0);
        float4 o;
        o.x = v0 + xr.x; o.y = v1 + xr.y; o.z = v2 + xr.z; o.w = v3 + xr.w;
        *(float4*)(out + (size_t)node * NDIM + c0) = o;
    }
}

extern "C" void kernel_launch(void* const* d_in, const int* in_sizes, int n_in,
                              void* d_out, int out_size, void* d_ws, size_t ws_size,
                              hipStream_t stream) {
    const float* x = (const float*)d_in[0];
    const unsigned* edge_w = (const unsigned*)d_in[1];
    const float* W = (const float*)d_in[2];
    const float* b = (const float*)d_in[3];
    float* out = (float*)d_out;

    const int N = in_sizes[0] / NDIM;          // 50000
    const int E = in_sizes[1] / 2;             // 625000
    const int nbuck = (N + (1 << BSH) - 1) >> BSH;   // 98
    const int chunk = (E + NB_A - 1) / NB_A;   // edges per bucketing block
    const int ntiles = (N + 63) / 64;          // 782

    char* ws = (char*)d_ws;
    unsigned short* hp = (unsigned short*)ws;                             // N*128 bf16
    float* dis   = (float*)(ws + (size_t)N * NDIM * sizeof(short));       // N
    int*   off   = (int*)((char*)dis + (size_t)N * sizeof(float));        // N+1
    int*   adj   = (int*)((char*)off + (size_t)(N + 4) * sizeof(int));    // E
    unsigned* ebuf = (unsigned*)((char*)adj + (size_t)E * sizeof(int));   // E
    int*   hist  = (int*)((char*)ebuf + (size_t)E * sizeof(unsigned));    // nbuck*NB_A
    int*   btot  = (int*)((char*)hist + (size_t)128 * NB_A * sizeof(int));// nbuck
    int*   bbase = (int*)((char*)btot + (size_t)128 * sizeof(int));       // nbuck
    int*   flag  = (int*)((char*)bbase + (size_t)128 * sizeof(int));      // 1

    detect_kernel<<<1, 256, 0, stream>>>(edge_w, flag);
    hist_kernel<<<NB_A, 256, 0, stream>>>(edge_w, flag, hist, E, nbuck, chunk);
    scanhist_kernel<<<nbuck, 1024, 0, stream>>>(hist, btot, NB_A);
    scanbuck_kernel<<<1, 128, 0, stream>>>(btot, bbase, nbuck, off, N, E);
    bucket_kernel<<<NB_A, 256, 0, stream>>>(edge_w, flag, hist, bbase, ebuf, E, nbuck, chunk);
    csr_kernel<<<nbuck, 512, 0, stream>>>(ebuf, bbase, btot, adj, off, dis, N);

    gemm_kernel<<<391, 256, 0, stream>>>(x, W, dis, hp, N, ntiles);

    int waves = (N + 1) / 2;                   // 2 nodes per wave
    gather_kernel<<<(waves + 3) / 4, 256, 0, stream>>>(hp, x, off, adj, dis, b, out, N);
}

// Round 8
// 78.312 us; speedup vs baseline: 1.0809x; 1.0809x over previous
//
#include <hip/hip_runtime.h>
#include <hip/hip_bf16.h>
#include <stdint.h>

#define NDIM 128
#define LDK 136      // padded K stride (shorts) for Wt rows
#define BSH 9        // bucket shift: 512 nodes per bucket
#define NB_A 1024    // bucketing grid
#define BCAP 9216    // per-bucket staging capacity (expected ~6400)

typedef __attribute__((ext_vector_type(8))) short bf16x8;
typedef __attribute__((ext_vector_type(4))) float f32x4;

__device__ __forceinline__ unsigned short f2bf(float f) {
    unsigned u = __float_as_uint(f);
    unsigned r = u + 0x7fffu + ((u >> 16) & 1u);   // round-to-nearest-even
    return (unsigned short)(r >> 16);
}
__device__ __forceinline__ float bf2f(unsigned short s) {
    return __uint_as_float(((unsigned)s) << 16);
}

// -------- edge accessor handling int64 vs int32 raw layout ------------------
__device__ __forceinline__ void load_edge(const unsigned* __restrict__ w, int is64, int E,
                                          int e, int& s, int& d) {
    if (is64) {
        s = (int)w[(size_t)2 * e];
        d = (int)w[(size_t)2 * E + (size_t)2 * e];
    } else {
        s = (int)w[e];
        d = (int)w[(size_t)E + e];
    }
}

// Per-block int64/int32 self-detection: sample 256 odd words of this block's
// chunk. int64 (values < 2^31) => all hi-words zero. For int32 random indices
// P(all 256 sampled words zero) ~ (2e-5)^256 ~ 0.
__device__ __forceinline__ int detect_is64(const unsigned* __restrict__ w,
                                           int lo, int hi, int E, int t, int* nzflag) {
    if (t == 0) *nzflag = 0;
    __syncthreads();
    int k = lo + t;
    if (k < hi && w[2 * (size_t)k + 1] != 0u) atomicOr(nzflag, 1);
    __syncthreads();
    return *nzflag ? 0 : 1;
}

// -------- hist: per-block bucket histogram + W->bf16T prep (blocks 0..63) ---
__global__ __launch_bounds__(256) void hist_kernel(const unsigned* __restrict__ w,
                                                   const float* __restrict__ W,
                                                   unsigned short* __restrict__ WbfT,
                                                   int* __restrict__ hist,
                                                   int* __restrict__ lock,
                                                   int E, int nbuck, int chunk) {
    __shared__ int h[128];
    __shared__ int nzflag;
    int t = threadIdx.x;
    if (t < 128) h[t] = 0;
    if (t == 0 && blockIdx.x == 0) *lock = 0;          // reset for scanhist
    int lo = blockIdx.x * chunk;
    int hi = lo + chunk; if (hi > E) hi = E;
    int is64 = detect_is64(w, lo, hi, E, t, &nzflag);  // includes barriers

    // W transpose+convert: WbfT[c*128+k] = bf16(W[k*128+c]) (blocks 0..63)
    if (blockIdx.x < 64) {
        int idx = blockIdx.x * 256 + t;
        int k = idx >> 7, c = idx & 127;
        WbfT[c * 128 + k] = f2bf(W[idx]);
    }

    for (int e = lo + t; e < hi; e += 256) {
        int s, d; load_edge(w, is64, E, e, s, d);
        atomicAdd(&h[d >> BSH], 1);
    }
    __syncthreads();
    if (t < nbuck) hist[(size_t)t * gridDim.x + blockIdx.x] = h[t];
}

// -------- scanhist: per-bucket scan of block-counts + fused bucket-total scan
__global__ __launch_bounds__(1024) void scanhist_kernel(int* __restrict__ hist,
                                                        int* __restrict__ btot,
                                                        int* __restrict__ bbase,
                                                        int* __restrict__ off,
                                                        int* __restrict__ lock,
                                                        int NB, int nbuck, int N, int E) {
    __shared__ int s[1024];
    __shared__ int amlast;
    int t = threadIdx.x;
    if (t == 0) amlast = 0;
    size_t base = (size_t)blockIdx.x * NB;
    int v = hist[base + t];
    s[t] = v;
    __syncthreads();
    for (int d = 1; d < 1024; d <<= 1) {
        int add = (t >= d) ? s[t - d] : 0;
        __syncthreads();
        s[t] += add;
        __syncthreads();
    }
    hist[base + t] = s[t] - v;            // exclusive within bucket
    if (t == 1023) {
        atomicExch(&btot[blockIdx.x], s[1023]);   // device-scope store
        __threadfence();
        int prev = atomicAdd(lock, 1);
        amlast = (prev == nbuck - 1) ? 1 : 0;
    }
    __syncthreads();
    if (amlast) {                          // last block: scan bucket totals
        int v2 = (t < nbuck) ? atomicAdd(&btot[t], 0) : 0;   // device-scope read
        s[t] = v2;
        __syncthreads();
        for (int d = 1; d < 128; d <<= 1) {
            int add = (t >= d && t < 128) ? s[t - d] : 0;
            __syncthreads();
            if (t < 128) s[t] += add;
            __syncthreads();
        }
        if (t < nbuck) bbase[t] = s[t] - v2;   // exclusive
        if (t == 0) off[N] = E;
    }
}

// -------- bucket scatter: packed (src<<9 | local) into reserved runs --------
__global__ __launch_bounds__(256) void bucket_kernel(const unsigned* __restrict__ w,
                                                     const int* __restrict__ hist,
                                                     const int* __restrict__ bbase,
                                                     unsigned* __restrict__ ebuf,
                                                     int E, int nbuck, int chunk) {
    __shared__ int cur[128];
    __shared__ int nzflag;
    int t = threadIdx.x;
    if (t < nbuck) cur[t] = bbase[t] + hist[(size_t)t * gridDim.x + blockIdx.x];
    int lo = blockIdx.x * chunk;
    int hi = lo + chunk; if (hi > E) hi = E;
    int is64 = detect_is64(w, lo, hi, E, t, &nzflag);  // includes barriers
    for (int e = lo + t; e < hi; e += 256) {
        int s, d; load_edge(w, is64, E, e, s, d);
        int b = d >> BSH;
        int p = atomicAdd(&cur[b], 1);    // LDS atomic
        ebuf[p] = ((unsigned)s << BSH) | (unsigned)(d & ((1 << BSH) - 1));
    }
}

// -------- per-bucket CSR build: cnt/dis/off/adj, all coalesced --------------
__global__ __launch_bounds__(512) void csr_kernel(const unsigned* __restrict__ ebuf,
                                                  const int* __restrict__ bbase,
                                                  const int* __restrict__ btot,
                                                  int* __restrict__ adj,
                                                  int* __restrict__ off,
                                                  float* __restrict__ dis,
                                                  int N) {
    __shared__ int lcnt[512];
    __shared__ int lscan[512];
    __shared__ int cur[512];
    __shared__ int tile[BCAP];
    int b = blockIdx.x, t = threadIdx.x;
    int start = bbase[b], cnt = btot[b];
    lcnt[t] = 0;
    __syncthreads();
    for (int i = t; i < cnt; i += 512) atomicAdd(&lcnt[ebuf[start + i] & 511], 1);
    __syncthreads();
    int v = lcnt[t];
    lscan[t] = v;
    __syncthreads();
    for (int d = 1; d < 512; d <<= 1) {
        int add = (t >= d) ? lscan[t - d] : 0;
        __syncthreads();
        lscan[t] += add;
        __syncthreads();
    }
    int ex = lscan[t] - v;                 // exclusive
    int node = (b << BSH) + t;
    if (node < N) {
        off[node] = start + ex;
        dis[node] = rsqrtf((float)(v + 1));
    }
    cur[t] = ex;
    __syncthreads();
    if (cnt <= BCAP) {
        for (int i = t; i < cnt; i += 512) {
            unsigned wo = ebuf[start + i];
            int p = atomicAdd(&cur[wo & 511], 1);
            tile[p] = (int)(wo >> BSH);
        }
        __syncthreads();
        for (int i = t; i < cnt; i += 512) adj[start + i] = tile[i];
    } else {                               // overflow fallback (never for this input)
        for (int i = t; i < cnt; i += 512) {
            unsigned wo = ebuf[start + i];
            int p = atomicAdd(&cur[wo & 511], 1);
            adj[start + p] = (int)(wo >> BSH);
        }
    }
}

// -------- h' = (x @ W) * dis[row], bf16 out (MFMA 16x16x32) -----------------
__global__ __launch_bounds__(256) void gemm_kernel(const float* __restrict__ x,
                                                   const unsigned short* __restrict__ WbfT,
                                                   const float* __restrict__ dis,
                                                   unsigned short* __restrict__ hp, int N) {
    __shared__ unsigned short Wt[NDIM][LDK];   // Wt[c][k]
    int tid = threadIdx.x;
    for (int ch = tid; ch < 2048; ch += 256) { // 2048 chunks of 8 shorts
        int c = ch >> 4;
        int k8 = (ch & 15) << 3;
        bf16x8 v = *(const bf16x8*)(WbfT + c * 128 + k8);
        *(bf16x8*)&Wt[c][k8] = v;
    }
    __syncthreads();

    const int lane = tid & 63;
    const int wv = tid >> 6;
    const int rowbase = blockIdx.x * 64 + wv * 16;
    const int l15 = lane & 15;
    const int kg = lane >> 4;          // 0..3
    const int arow = rowbase + l15;

    bf16x8 a[4];
#pragma unroll
    for (int s = 0; s < 4; ++s) {
        bf16x8 tt;
        if (arow < N) {
            const float* p = x + (size_t)arow * NDIM + s * 32 + kg * 8;
            float4 f0 = *(const float4*)p;
            float4 f1 = *(const float4*)(p + 4);
            tt[0] = (short)f2bf(f0.x); tt[1] = (short)f2bf(f0.y);
            tt[2] = (short)f2bf(f0.z); tt[3] = (short)f2bf(f0.w);
            tt[4] = (short)f2bf(f1.x); tt[5] = (short)f2bf(f1.y);
            tt[6] = (short)f2bf(f1.z); tt[7] = (short)f2bf(f1.w);
        } else {
#pragma unroll
            for (int e = 0; e < 8; ++e) tt[e] = 0;
        }
        a[s] = tt;
    }

    f32x4 acc[8];
#pragma unroll
    for (int ct = 0; ct < 8; ++ct) acc[ct] = (f32x4){0.f, 0.f, 0.f, 0.f};

#pragma unroll
    for (int ct = 0; ct < 8; ++ct) {
#pragma unroll
        for (int s = 0; s < 4; ++s) {
            bf16x8 bb = *(const bf16x8*)&Wt[ct * 16 + l15][s * 32 + kg * 8];
            acc[ct] = __builtin_amdgcn_mfma_f32_16x16x32_bf16(a[s], bb, acc[ct], 0, 0, 0);
        }
    }

    const int r0 = rowbase + kg * 4;
    float dv[4];
#pragma unroll
    for (int j = 0; j < 4; ++j) dv[j] = (r0 + j < N) ? dis[r0 + j] : 0.f;
#pragma unroll
    for (int ct = 0; ct < 8; ++ct) {
        int col = ct * 16 + l15;
#pragma unroll
        for (int j = 0; j < 4; ++j) {
            int r = r0 + j;
            if (r < N) hp[(size_t)r * NDIM + col] = f2bf(acc[ct][j] * dv[j]);
        }
    }
}

// -------- JAX partitionable threefry bits, counter (0, ctr), key (0, 42) ----
__device__ __forceinline__ unsigned rotl32(unsigned v, int d) {
    return (v << d) | (v >> (32 - d));
}
__device__ __forceinline__ unsigned tf_bits(unsigned ctr) {
    unsigned x0 = 0u, x1 = ctr;
    const unsigned ks0 = 0u, ks1 = 42u, ks2 = 0u ^ 42u ^ 0x1BD11BDAu;
    x0 += ks0; x1 += ks1;
#define RND(r) { x0 += x1; x1 = rotl32(x1, (r)); x1 ^= x0; }
    RND(13) RND(15) RND(26) RND(6)   x0 += ks1; x1 += ks2 + 1u;
    RND(17) RND(29) RND(16) RND(24)  x0 += ks2; x1 += ks0 + 2u;
    RND(13) RND(15) RND(26) RND(6)   x0 += ks0; x1 += ks1 + 3u;
    RND(17) RND(29) RND(16) RND(24)  x0 += ks1; x1 += ks2 + 4u;
    RND(13) RND(15) RND(26) RND(6)   x0 += ks2; x1 += ks0 + 5u;
#undef RND
    return x0 ^ x1;
}

// -------- gather + finalize: 2 nodes per wave, 8-deep MLP -------------------
__global__ __launch_bounds__(256) void gather_kernel(const unsigned short* __restrict__ hp,
                                                     const float* __restrict__ x,
                                                     const int* __restrict__ off,
                                                     const int* __restrict__ adj,
                                                     const float* __restrict__ dis,
                                                     const float* __restrict__ b,
                                                     float* __restrict__ out, int N) {
    int wid = (int)((blockIdx.x * 256u + threadIdx.x) >> 6);
    int lane = threadIdx.x & 63;
    int half = lane >> 5;              // which node of the pair
    int l32 = lane & 31;
    int node = wid * 2 + half;
    bool valid = node < N;
    int nodec = valid ? node : N - 1;
    const float dn = dis[nodec];
    const int c0 = l32 * 4;            // 4 bf16 columns per lane
    const unsigned short* hpc = hp + c0;

    // dropout bits (independent — hoisted to overlap gather latency)
    unsigned ctr = (unsigned)(nodec * NDIM + c0);
    unsigned bt0 = tf_bits(ctr);
    unsigned bt1 = tf_bits(ctr + 1u);
    unsigned bt2 = tf_bits(ctr + 2u);
    unsigned bt3 = tf_bits(ctr + 3u);

    // self-loop: h'[node] (already contains dis[node])
    uint2 hv = *(const uint2*)(hpc + (size_t)nodec * NDIM);
    float a00 = bf2f((unsigned short)hv.x), a01 = bf2f((unsigned short)(hv.x >> 16));
    float a02 = bf2f((unsigned short)hv.y), a03 = bf2f((unsigned short)(hv.y >> 16));
    float a10 = 0.f, a11 = 0.f, a12 = 0.f, a13 = 0.f;
    float a20 = 0.f, a21 = 0.f, a22 = 0.f, a23 = 0.f;
    float a30 = 0.f, a31 = 0.f, a32 = 0.f, a33 = 0.f;

    int k0 = valid ? off[nodec] : 0;
    int k1 = valid ? off[nodec + 1] : 0;
    int kb = k0;
    const int sbase = half << 5;
    while (kb < k1) {
        int nb = k1 - kb; if (nb > 32) nb = 32;
        int myadj = (kb + l32 < k1) ? adj[kb + l32] : 0;
        int j = 0;
        for (; j + 8 <= nb; j += 8) {          // 8 independent loads in flight
            int s0 = __shfl(myadj, sbase + j);
            int s1 = __shfl(myadj, sbase + j + 1);
            int s2 = __shfl(myadj, sbase + j + 2);
            int s3 = __shfl(myadj, sbase + j + 3);
            int s4 = __shfl(myadj, sbase + j + 4);
            int s5 = __shfl(myadj, sbase + j + 5);
            int s6 = __shfl(myadj, sbase + j + 6);
            int s7 = __shfl(myadj, sbase + j + 7);
            uint2 v0 = *(const uint2*)(hpc + (size_t)s0 * NDIM);
            uint2 v1 = *(const uint2*)(hpc + (size_t)s1 * NDIM);
            uint2 v2 = *(const uint2*)(hpc + (size_t)s2 * NDIM);
            uint2 v3 = *(const uint2*)(hpc + (size_t)s3 * NDIM);
            uint2 v4 = *(const uint2*)(hpc + (size_t)s4 * NDIM);
            uint2 v5 = *(const uint2*)(hpc + (size_t)s5 * NDIM);
            uint2 v6 = *(const uint2*)(hpc + (size_t)s6 * NDIM);
            uint2 v7 = *(const uint2*)(hpc + (size_t)s7 * NDIM);
            a00 += bf2f((unsigned short)v0.x); a01 += bf2f((unsigned short)(v0.x >> 16));
            a02 += bf2f((unsigned short)v0.y); a03 += bf2f((unsigned short)(v0.y >> 16));
            a10 += bf2f((unsigned short)v1.x); a11 += bf2f((unsigned short)(v1.x >> 16));
            a12 += bf2f((unsigned short)v1.y); a13 += bf2f((unsigned short)(v1.y >> 16));
            a20 += bf2f((unsigned short)v2.x); a21 += bf2f((unsigned short)(v2.x >> 16));
            a22 += bf2f((unsigned short)v2.y); a23 += bf2f((unsigned short)(v2.y >> 16));
            a30 += bf2f((unsigned short)v3.x); a31 += bf2f((unsigned short)(v3.x >> 16));
            a32 += bf2f((unsigned short)v3.y); a33 += bf2f((unsigned short)(v3.y >> 16));
            a00 += bf2f((unsigned short)v4.x); a01 += bf2f((unsigned short)(v4.x >> 16));
            a02 += bf2f((unsigned short)v4.y); a03 += bf2f((unsigned short)(v4.y >> 16));
            a10 += bf2f((unsigned short)v5.x); a11 += bf2f((unsigned short)(v5.x >> 16));
            a12 += bf2f((unsigned short)v5.y); a13 += bf2f((unsigned short)(v5.y >> 16));
            a20 += bf2f((unsigned short)v6.x); a21 += bf2f((unsigned short)(v6.x >> 16));
            a22 += bf2f((unsigned short)v6.y); a23 += bf2f((unsigned short)(v6.y >> 16));
            a30 += bf2f((unsigned short)v7.x); a31 += bf2f((unsigned short)(v7.x >> 16));
            a32 += bf2f((unsigned short)v7.y); a33 += bf2f((unsigned short)(v7.y >> 16));
        }
        if (j + 4 <= nb) {
            int s0 = __shfl(myadj, sbase + j);
            int s1 = __shfl(myadj, sbase + j + 1);
            int s2 = __shfl(myadj, sbase + j + 2);
            int s3 = __shfl(myadj, sbase + j + 3);
            uint2 v0 = *(const uint2*)(hpc + (size_t)s0 * NDIM);
            uint2 v1 = *(const uint2*)(hpc + (size_t)s1 * NDIM);
            uint2 v2 = *(const uint2*)(hpc + (size_t)s2 * NDIM);
            uint2 v3 = *(const uint2*)(hpc + (size_t)s3 * NDIM);
            a00 += bf2f((unsigned short)v0.x); a01 += bf2f((unsigned short)(v0.x >> 16));
            a02 += bf2f((unsigned short)v0.y); a03 += bf2f((unsigned short)(v0.y >> 16));
            a10 += bf2f((unsigned short)v1.x); a11 += bf2f((unsigned short)(v1.x >> 16));
            a12 += bf2f((unsigned short)v1.y); a13 += bf2f((unsigned short)(v1.y >> 16));
            a20 += bf2f((unsigned short)v2.x); a21 += bf2f((unsigned short)(v2.x >> 16));
            a22 += bf2f((unsigned short)v2.y); a23 += bf2f((unsigned short)(v2.y >> 16));
            a30 += bf2f((unsigned short)v3.x); a31 += bf2f((unsigned short)(v3.x >> 16));
            a32 += bf2f((unsigned short)v3.y); a33 += bf2f((unsigned short)(v3.y >> 16));
            j += 4;
        }
        for (; j < nb; ++j) {
            int s = __shfl(myadj, sbase + j);
            uint2 v = *(const uint2*)(hpc + (size_t)s * NDIM);
            a00 += bf2f((unsigned short)v.x); a01 += bf2f((unsigned short)(v.x >> 16));
            a02 += bf2f((unsigned short)v.y); a03 += bf2f((unsigned short)(v.y >> 16));
        }
        kb += nb;
    }

    float c0s = (a00 + a10) + (a20 + a30);
    float c1s = (a01 + a11) + (a21 + a31);
    float c2s = (a02 + a12) + (a22 + a32);
    float c3s = (a03 + a13) + (a23 + a33);

    float4 bb = *(const float4*)(b + c0);
    float v0 = fmaxf(fmaf(dn, c0s, bb.x), 0.f);
    float v1 = fmaxf(fmaf(dn, c1s, bb.y), 0.f);
    float v2 = fmaxf(fmaf(dn, c2s, bb.z), 0.f);
    float v3 = fmaxf(fmaf(dn, c3s, bb.w), 0.f);

    v0 = (bt0 >> 31) ? 0.f : v0 * 2.f;
    v1 = (bt1 >> 31) ? 0.f : v1 * 2.f;
    v2 = (bt2 >> 31) ? 0.f : v2 * 2.f;
    v3 = (bt3 >> 31) ? 0.f : v3 * 2.f;

    if (valid) {
        float4 xr = *(const float4*)(x + (size_t)node * NDIM + c0);
        float4 o;
        o.x = v0 + xr.x; o.y = v1 + xr.y; o.z = v2 + xr.z; o.w = v3 + xr.w;
        *(float4*)(out + (size_t)node * NDIM + c0) = o;
    }
}

extern "C" void kernel_launch(void* const* d_in, const int* in_sizes, int n_in,
                              void* d_out, int out_size, void* d_ws, size_t ws_size,
                              hipStream_t stream) {
    const float* x = (const float*)d_in[0];
    const unsigned* edge_w = (const unsigned*)d_in[1];
    const float* W = (const float*)d_in[2];
    const float* b = (const float*)d_in[3];
    float* out = (float*)d_out;

    const int N = in_sizes[0] / NDIM;          // 50000
    const int E = in_sizes[1] / 2;             // 625000
    const int nbuck = (N + (1 << BSH) - 1) >> BSH;   // 98
    const int chunk = (E + NB_A - 1) / NB_A;   // edges per bucketing block

    char* ws = (char*)d_ws;
    unsigned short* hp = (unsigned short*)ws;                             // N*128 bf16
    float* dis   = (float*)(ws + (size_t)N * NDIM * sizeof(short));       // N
    int*   off   = (int*)((char*)dis + (size_t)N * sizeof(float));        // N+1
    int*   adj   = (int*)((char*)off + (size_t)(N + 4) * sizeof(int));    // E
    unsigned* ebuf = (unsigned*)((char*)adj + (size_t)E * sizeof(int));   // E
    int*   hist  = (int*)((char*)ebuf + (size_t)E * sizeof(unsigned));    // nbuck*NB_A
    int*   btot  = (int*)((char*)hist + (size_t)128 * NB_A * sizeof(int));// 128
    int*   bbase = (int*)((char*)btot + (size_t)128 * sizeof(int));       // 128
    int*   lock  = (int*)((char*)bbase + (size_t)128 * sizeof(int));      // 1
    unsigned short* WbfT = (unsigned short*)((char*)lock + 64);           // 16384 bf16

    hist_kernel<<<NB_A, 256, 0, stream>>>(edge_w, W, WbfT, hist, lock, E, nbuck, chunk);
    scanhist_kernel<<<nbuck, 1024, 0, stream>>>(hist, btot, bbase, off, lock, NB_A, nbuck, N, E);
    bucket_kernel<<<NB_A, 256, 0, stream>>>(edge_w, hist, bbase, ebuf, E, nbuck, chunk);
    csr_kernel<<<nbuck, 512, 0, stream>>>(ebuf, bbase, btot, adj, off, dis, N);

    gemm_kernel<<<(N + 63) / 64, 256, 0, stream>>>(x, WbfT, dis, hp, N);

    int waves = (N + 1) / 2;                   // 2 nodes per wave
    gather_kernel<<<(waves + 3) / 4, 256, 0, stream>>>(hp, x, off, adj, dis, b, out, N);
}

// Round 11
// 73.572 us; speedup vs baseline: 1.1506x; 1.0644x over previous
//
#include <hip/hip_runtime.h>
#include <hip/hip_bf16.h>
#include <stdint.h>

#define NDIM 128
#define LDK 136      // padded K stride (shorts) for Wt rows
#define BSH 9        // bucket shift: 512 nodes per bucket
#define NB_A 1024    // bucketing grid
#define BCAP 9216    // per-bucket staging capacity (expected max ~6700)

typedef __attribute__((ext_vector_type(8))) short bf16x8;
typedef __attribute__((ext_vector_type(4))) float f32x4;

__device__ __forceinline__ unsigned short f2bf(float f) {
    unsigned u = __float_as_uint(f);
    unsigned r = u + 0x7fffu + ((u >> 16) & 1u);   // round-to-nearest-even
    return (unsigned short)(r >> 16);
}
__device__ __forceinline__ float bf2f(unsigned short s) {
    return __uint_as_float(((unsigned)s) << 16);
}

__device__ __forceinline__ void load_edge(const unsigned* __restrict__ w, int is64, int E,
                                          int e, int& s, int& d) {
    if (is64) {
        s = (int)w[(size_t)2 * e];
        d = (int)w[(size_t)2 * E + (size_t)2 * e];
    } else {
        s = (int)w[e];
        d = (int)w[(size_t)E + e];
    }
}

// Per-block int64/int32 self-detection (256 odd-word samples of own chunk).
__device__ __forceinline__ int detect_is64(const unsigned* __restrict__ w,
                                           int lo, int hi, int t, int* nzflag) {
    if (t == 0) *nzflag = 0;
    __syncthreads();
    int k = lo + t;
    if (k < hi && w[2 * (size_t)k + 1] != 0u) atomicOr(nzflag, 1);
    __syncthreads();
    return *nzflag ? 0 : 1;
}

// -------- hist: per-block bucket histogram + W->bf16T prep (blocks 0..63) ---
__global__ __launch_bounds__(256) void hist_kernel(const unsigned* __restrict__ w,
                                                   const float* __restrict__ W,
                                                   unsigned short* __restrict__ WbfT,
                                                   int* __restrict__ hist,
                                                   int* __restrict__ lock,
                                                   int E, int nbuck, int chunk) {
    __shared__ int h[128];
    __shared__ int nzflag;
    int t = threadIdx.x;
    if (t < 128) h[t] = 0;
    if (t == 0 && blockIdx.x == 0) *lock = 0;          // reset for scanhist
    int lo = blockIdx.x * chunk;
    int hi = lo + chunk; if (hi > E) hi = E;
    int is64 = detect_is64(w, lo, hi, t, &nzflag);     // barriers inside

    // W transpose+convert: WbfT[c*128+k] = bf16(W[k*128+c]) (blocks 0..63)
    if (blockIdx.x < 64) {
        int idx = blockIdx.x * 256 + t;
        int k = idx >> 7, c = idx & 127;
        WbfT[c * 128 + k] = f2bf(W[idx]);
    }

    for (int e = lo + t; e < hi; e += 256) {
        int s, d; load_edge(w, is64, E, e, s, d);
        atomicAdd(&h[d >> BSH], 1);
    }
    __syncthreads();
    if (t < nbuck) hist[(size_t)t * gridDim.x + blockIdx.x] = h[t];
}

// -------- scanhist: per-bucket scan of block-counts + fused bucket-total scan
__global__ __launch_bounds__(1024) void scanhist_kernel(int* __restrict__ hist,
                                                        int* __restrict__ btot,
                                                        int* __restrict__ bbase,
                                                        int* __restrict__ off,
                                                        int* __restrict__ lock,
                                                        int NB, int nbuck, int N, int E) {
    __shared__ int s[1024];
    __shared__ int amlast;
    int t = threadIdx.x;
    if (t == 0) amlast = 0;
    size_t base = (size_t)blockIdx.x * NB;
    int v = hist[base + t];
    s[t] = v;
    __syncthreads();
    for (int d = 1; d < 1024; d <<= 1) {
        int add = (t >= d) ? s[t - d] : 0;
        __syncthreads();
        s[t] += add;
        __syncthreads();
    }
    hist[base + t] = s[t] - v;            // exclusive within bucket
    if (t == 1023) {
        atomicExch(&btot[blockIdx.x], s[1023]);   // device-scope store
        __threadfence();
        int prev = atomicAdd(lock, 1);
        amlast = (prev == nbuck - 1) ? 1 : 0;
    }
    __syncthreads();
    if (amlast) {                          // last block: scan bucket totals
        int v2 = (t < nbuck) ? atomicAdd(&btot[t], 0) : 0;   // device-scope read
        s[t] = v2;
        __syncthreads();
        for (int d = 1; d < 128; d <<= 1) {
            int add = (t >= d && t < 128) ? s[t - d] : 0;
            __syncthreads();
            if (t < 128) s[t] += add;
            __syncthreads();
        }
        if (t < nbuck) bbase[t] = s[t] - v2;   // exclusive
        if (t == 0) off[N] = E;
    }
}

// -------- bucket scatter: packed (src<<9 | local) into reserved runs --------
__global__ __launch_bounds__(256) void bucket_kernel(const unsigned* __restrict__ w,
                                                     const int* __restrict__ hist,
                                                     const int* __restrict__ bbase,
                                                     unsigned* __restrict__ ebuf,
                                                     int E, int nbuck, int chunk) {
    __shared__ int cur[128];
    __shared__ int nzflag;
    int t = threadIdx.x;
    if (t < nbuck) cur[t] = bbase[t] + hist[(size_t)t * gridDim.x + blockIdx.x];
    int lo = blockIdx.x * chunk;
    int hi = lo + chunk; if (hi > E) hi = E;
    int is64 = detect_is64(w, lo, hi, t, &nzflag);     // barriers inside
    for (int e = lo + t; e < hi; e += 256) {
        int s, d; load_edge(w, is64, E, e, s, d);
        int b = d >> BSH;
        int p = atomicAdd(&cur[b], 1);    // LDS atomic
        ebuf[p] = ((unsigned)s << BSH) | (unsigned)(d & 511);
    }
}

// -------- fused: csr build (blocks 0..nbuck-1) || gemm (blocks nbuck..) -----
// csr: per-bucket CSR + dis;  gemm: hp = bf16(x @ W), 8 waves, 128-row tiles
__global__ __launch_bounds__(512) void csrgemm_kernel(const unsigned* __restrict__ ebuf,
                                                      const int* __restrict__ bbase,
                                                      const int* __restrict__ btot,
                                                      int* __restrict__ adj,
                                                      int* __restrict__ off,
                                                      float* __restrict__ dis,
                                                      const float* __restrict__ x,
                                                      const unsigned short* __restrict__ WbfT,
                                                      unsigned short* __restrict__ hp,
                                                      int N, int nbuck) {
    __shared__ union {
        struct { int lcnt[512]; int lscan[512]; int cur[512]; int tile[BCAP]; } cs;
        unsigned short Wt[NDIM][LDK];
    } u;
    int t = threadIdx.x;
    if (blockIdx.x < nbuck) {
        // ----- csr branch (R8-proven, 512 threads) -----
        int b = blockIdx.x;
        int start = bbase[b], cnt = btot[b];
        u.cs.lcnt[t] = 0;
        __syncthreads();
        for (int i = t; i < cnt; i += 512) atomicAdd(&u.cs.lcnt[ebuf[start + i] & 511], 1);
        __syncthreads();
        int v = u.cs.lcnt[t];
        u.cs.lscan[t] = v;
        __syncthreads();
        for (int d = 1; d < 512; d <<= 1) {
            int add = (t >= d) ? u.cs.lscan[t - d] : 0;
            __syncthreads();
            u.cs.lscan[t] += add;
            __syncthreads();
        }
        int ex = u.cs.lscan[t] - v;            // exclusive
        int node = (b << BSH) + t;
        if (node < N) {
            off[node] = start + ex;
            dis[node] = rsqrtf((float)(v + 1));
        }
        u.cs.cur[t] = ex;
        __syncthreads();
        if (cnt <= BCAP) {
            for (int i = t; i < cnt; i += 512) {
                unsigned wo = ebuf[start + i];
                int p = atomicAdd(&u.cs.cur[wo & 511], 1);
                u.cs.tile[p] = (int)(wo >> BSH);
            }
            __syncthreads();
            for (int i = t; i < cnt; i += 512) adj[start + i] = u.cs.tile[i];
        } else {
            for (int i = t; i < cnt; i += 512) {
                unsigned wo = ebuf[start + i];
                int p = atomicAdd(&u.cs.cur[wo & 511], 1);
                adj[start + p] = (int)(wo >> BSH);
            }
        }
    } else {
        // ----- gemm branch: hp = bf16(x @ W), 8 waves x 16 rows = 128 rows --
        for (int ch = t; ch < 2048; ch += 512) {
            int c = ch >> 4, k8 = (ch & 15) << 3;
            *(bf16x8*)&u.Wt[c][k8] = *(const bf16x8*)(WbfT + c * 128 + k8);
        }
        __syncthreads();
        const int lane = t & 63;
        const int wv = t >> 6;                 // 0..7
        const int l15 = lane & 15;
        const int kg = lane >> 4;              // 0..3
        const int rowbase = (blockIdx.x - nbuck) * 128 + wv * 16;
        const int arow = rowbase + l15;

        bf16x8 a[4];
#pragma unroll
        for (int s = 0; s < 4; ++s) {
            bf16x8 tt;
            if (arow < N) {
                const float* p = x + (size_t)arow * NDIM + s * 32 + kg * 8;
                float4 f0 = *(const float4*)p;
                float4 f1 = *(const float4*)(p + 4);
                tt[0] = (short)f2bf(f0.x); tt[1] = (short)f2bf(f0.y);
                tt[2] = (short)f2bf(f0.z); tt[3] = (short)f2bf(f0.w);
                tt[4] = (short)f2bf(f1.x); tt[5] = (short)f2bf(f1.y);
                tt[6] = (short)f2bf(f1.z); tt[7] = (short)f2bf(f1.w);
            } else {
#pragma unroll
                for (int e = 0; e < 8; ++e) tt[e] = 0;
            }
            a[s] = tt;
        }

        f32x4 acc[8];
#pragma unroll
        for (int ct = 0; ct < 8; ++ct) acc[ct] = (f32x4){0.f, 0.f, 0.f, 0.f};
#pragma unroll
        for (int ct = 0; ct < 8; ++ct) {
#pragma unroll
            for (int s = 0; s < 4; ++s) {
                bf16x8 bb = *(const bf16x8*)&u.Wt[ct * 16 + l15][s * 32 + kg * 8];
                acc[ct] = __builtin_amdgcn_mfma_f32_16x16x32_bf16(a[s], bb, acc[ct], 0, 0, 0);
            }
        }

        const int r0 = rowbase + kg * 4;
#pragma unroll
        for (int ct = 0; ct < 8; ++ct) {
            int col = ct * 16 + l15;
#pragma unroll
            for (int j = 0; j < 4; ++j) {
                int r = r0 + j;
                if (r < N) hp[(size_t)r * NDIM + col] = f2bf(acc[ct][j]);
            }
        }
    }
}

// -------- JAX partitionable threefry bits, counter (0, ctr), key (0, 42) ----
__device__ __forceinline__ unsigned rotl32(unsigned v, int d) {
    return (v << d) | (v >> (32 - d));
}
__device__ __forceinline__ unsigned tf_bits(unsigned ctr) {
    unsigned x0 = 0u, x1 = ctr;
    const unsigned ks0 = 0u, ks1 = 42u, ks2 = 0u ^ 42u ^ 0x1BD11BDAu;
    x0 += ks0; x1 += ks1;
#define RND(r) { x0 += x1; x1 = rotl32(x1, (r)); x1 ^= x0; }
    RND(13) RND(15) RND(26) RND(6)   x0 += ks1; x1 += ks2 + 1u;
    RND(17) RND(29) RND(16) RND(24)  x0 += ks2; x1 += ks0 + 2u;
    RND(13) RND(15) RND(26) RND(6)   x0 += ks0; x1 += ks1 + 3u;
    RND(17) RND(29) RND(16) RND(24)  x0 += ks1; x1 += ks2 + 4u;
    RND(13) RND(15) RND(26) RND(6)   x0 += ks2; x1 += ks0 + 5u;
#undef RND
    return x0 ^ x1;
}

// -------- gather + finalize: 2 nodes per wave, 8-deep MLP, dis on the fly ---
__global__ __launch_bounds__(256) void gather_kernel(const unsigned short* __restrict__ hp,
                                                     const float* __restrict__ x,
                                                     const int* __restrict__ off,
                                                     const int* __restrict__ adj,
                                                     const float* __restrict__ dis,
                                                     const float* __restrict__ b,
                                                     float* __restrict__ out, int N) {
    int wid = (int)((blockIdx.x * 256u + threadIdx.x) >> 6);
    int lane = threadIdx.x & 63;
    int half = lane >> 5;
    int l32 = lane & 31;
    int node = wid * 2 + half;
    bool valid = node < N;
    int nodec = valid ? node : N - 1;
    const float dn = dis[nodec];
    const int c0 = l32 * 4;
    const unsigned short* hpc = hp + c0;

    unsigned ctr = (unsigned)(nodec * NDIM + c0);
    unsigned bt0 = tf_bits(ctr);
    unsigned bt1 = tf_bits(ctr + 1u);
    unsigned bt2 = tf_bits(ctr + 2u);
    unsigned bt3 = tf_bits(ctr + 3u);

    // self-loop: h[node] * dn  (full norm dn^2 applied via final dn*acc)
    uint2 hv = *(const uint2*)(hpc + (size_t)nodec * NDIM);
    float a00 = bf2f((unsigned short)hv.x) * dn, a01 = bf2f((unsigned short)(hv.x >> 16)) * dn;
    float a02 = bf2f((unsigned short)hv.y) * dn, a03 = bf2f((unsigned short)(hv.y >> 16)) * dn;
    float a10 = 0.f, a11 = 0.f, a12 = 0.f, a13 = 0.f;
    float a20 = 0.f, a21 = 0.f, a22 = 0.f, a23 = 0.f;
    float a30 = 0.f, a31 = 0.f, a32 = 0.f, a33 = 0.f;

    int k0 = valid ? off[nodec] : 0;
    int k1 = valid ? off[nodec + 1] : 0;
    int kb = k0;
    const int sbase = half << 5;
    while (kb < k1) {
        int nb = k1 - kb; if (nb > 32) nb = 32;
        int myadj = (kb + l32 < k1) ? adj[kb + l32] : 0;
        float mydis = dis[myadj];              // scattered 4B, L2-resident
        int j = 0;
        for (; j + 8 <= nb; j += 8) {
            int s0 = __shfl(myadj, sbase + j);
            int s1 = __shfl(myadj, sbase + j + 1);
            int s2 = __shfl(myadj, sbase + j + 2);
            int s3 = __shfl(myadj, sbase + j + 3);
            int s4 = __shfl(myadj, sbase + j + 4);
            int s5 = __shfl(myadj, sbase + j + 5);
            int s6 = __shfl(myadj, sbase + j + 6);
            int s7 = __shfl(myadj, sbase + j + 7);
            uint2 v0 = *(const uint2*)(hpc + (size_t)s0 * NDIM);
            uint2 v1 = *(const uint2*)(hpc + (size_t)s1 * NDIM);
            uint2 v2 = *(const uint2*)(hpc + (size_t)s2 * NDIM);
            uint2 v3 = *(const uint2*)(hpc + (size_t)s3 * NDIM);
            uint2 v4 = *(const uint2*)(hpc + (size_t)s4 * NDIM);
            uint2 v5 = *(const uint2*)(hpc + (size_t)s5 * NDIM);
            uint2 v6 = *(const uint2*)(hpc + (size_t)s6 * NDIM);
            uint2 v7 = *(const uint2*)(hpc + (size_t)s7 * NDIM);
            float n0 = __shfl(mydis, sbase + j);
            float n1 = __shfl(mydis, sbase + j + 1);
            float n2 = __shfl(mydis, sbase + j + 2);
            float n3 = __shfl(mydis, sbase + j + 3);
            float n4 = __shfl(mydis, sbase + j + 4);
            float n5 = __shfl(mydis, sbase + j + 5);
            float n6 = __shfl(mydis, sbase + j + 6);
            float n7 = __shfl(mydis, sbase + j + 7);
            a00 = fmaf(bf2f((unsigned short)v0.x), n0, a00);
            a01 = fmaf(bf2f((unsigned short)(v0.x >> 16)), n0, a01);
            a02 = fmaf(bf2f((unsigned short)v0.y), n0, a02);
            a03 = fmaf(bf2f((unsigned short)(v0.y >> 16)), n0, a03);
            a10 = fmaf(bf2f((unsigned short)v1.x), n1, a10);
            a11 = fmaf(bf2f((unsigned short)(v1.x >> 16)), n1, a11);
            a12 = fmaf(bf2f((unsigned short)v1.y), n1, a12);
            a13 = fmaf(bf2f((unsigned short)(v1.y >> 16)), n1, a13);
            a20 = fmaf(bf2f((unsigned short)v2.x), n2, a20);
            a21 = fmaf(bf2f((unsigned short)(v2.x >> 16)), n2, a21);
            a22 = fmaf(bf2f((unsigned short)v2.y), n2, a22);
            a23 = fmaf(bf2f((unsigned short)(v2.y >> 16)), n2, a23);
            a30 = fmaf(bf2f((unsigned short)v3.x), n3, a30);
            a31 = fmaf(bf2f((unsigned short)(v3.x >> 16)), n3, a31);
            a32 = fmaf(bf2f((unsigned short)v3.y), n3, a32);
            a33 = fmaf(bf2f((unsigned short)(v3.y >> 16)), n3, a33);
            a00 = fmaf(bf2f((unsigned short)v4.x), n4, a00);
            a01 = fmaf(bf2f((unsigned short)(v4.x >> 16)), n4, a01);
            a02 = fmaf(bf2f((unsigned short)v4.y), n4, a02);
            a03 = fmaf(bf2f((unsigned short)(v4.y >> 16)), n4, a03);
            a10 = fmaf(bf2f((unsigned short)v5.x), n5, a10);
            a11 = fmaf(bf2f((unsigned short)(v5.x >> 16)), n5, a11);
            a12 = fmaf(bf2f((unsigned short)v5.y), n5, a12);
            a13 = fmaf(bf2f((unsigned short)(v5.y >> 16)), n5, a13);
            a20 = fmaf(bf2f((unsigned short)v6.x), n6, a20);
            a21 = fmaf(bf2f((unsigned short)(v6.x >> 16)), n6, a21);
            a22 = fmaf(bf2f((unsigned short)v6.y), n6, a22);
            a23 = fmaf(bf2f((unsigned short)(v6.y >> 16)), n6, a23);
            a30 = fmaf(bf2f((unsigned short)v7.x), n7, a30);
            a31 = fmaf(bf2f((unsigned short)(v7.x >> 16)), n7, a31);
            a32 = fmaf(bf2f((unsigned short)v7.y), n7, a32);
            a33 = fmaf(bf2f((unsigned short)(v7.y >> 16)), n7, a33);
        }
        for (; j < nb; ++j) {
            int s = __shfl(myadj, sbase + j);
            float nn = __shfl(mydis, sbase + j);
            uint2 v = *(const uint2*)(hpc + (size_t)s * NDIM);
            a00 = fmaf(bf2f((unsigned short)v.x), nn, a00);
            a01 = fmaf(bf2f((unsigned short)(v.x >> 16)), nn, a01);
            a02 = fmaf(bf2f((unsigned short)v.y), nn, a02);
            a03 = fmaf(bf2f((unsigned short)(v.y >> 16)), nn, a03);
        }
        kb += nb;
    }

    float c0s = (a00 + a10) + (a20 + a30);
    float c1s = (a01 + a11) + (a21 + a31);
    float c2s = (a02 + a12) + (a22 + a32);
    float c3s = (a03 + a13) + (a23 + a33);

    float4 bb = *(const float4*)(b + c0);
    float v0 = fmaxf(fmaf(dn, c0s, bb.x), 0.f);
    float v1 = fmaxf(fmaf(dn, c1s, bb.y), 0.f);
    float v2 = fmaxf(fmaf(dn, c2s, bb.z), 0.f);
    float v3 = fmaxf(fmaf(dn, c3s, bb.w), 0.f);

    v0 = (bt0 >> 31) ? 0.f : v0 * 2.f;
    v1 = (bt1 >> 31) ? 0.f : v1 * 2.f;
    v2 = (bt2 >> 31) ? 0.f : v2 * 2.f;
    v3 = (bt3 >> 31) ? 0.f : v3 * 2.f;

    if (valid) {
        float4 xr = *(const float4*)(x + (size_t)node * NDIM + c0);
        float4 o;
        o.x = v0 + xr.x; o.y = v1 + xr.y; o.z = v2 + xr.z; o.w = v3 + xr.w;
        *(float4*)(out + (size_t)node * NDIM + c0) = o;
    }
}

extern "C" void kernel_launch(void* const* d_in, const int* in_sizes, int n_in,
                              void* d_out, int out_size, void* d_ws, size_t ws_size,
                              hipStream_t stream) {
    const float* x = (const float*)d_in[0];
    const unsigned* edge_w = (const unsigned*)d_in[1];
    const float* W = (const float*)d_in[2];
    const float* b = (const float*)d_in[3];
    float* out = (float*)d_out;

    const int N = in_sizes[0] / NDIM;          // 50000
    const int E = in_sizes[1] / 2;             // 625000
    const int nbuck = (N + (1 << BSH) - 1) >> BSH;   // 98
    const int chunk = (E + NB_A - 1) / NB_A;   // edges per bucketing block
    const int ntiles = (N + 127) / 128;        // 391 gemm tiles (128 rows each)

    char* ws = (char*)d_ws;
    unsigned short* hp = (unsigned short*)ws;                             // N*128 bf16
    float* dis   = (float*)(ws + (size_t)N * NDIM * sizeof(short));       // N
    int*   off   = (int*)((char*)dis + (size_t)N * sizeof(float));        // N+4
    int*   adj   = (int*)((char*)off + (size_t)(N + 4) * sizeof(int));    // E
    unsigned* ebuf = (unsigned*)((char*)adj + (size_t)E * sizeof(int));   // E
    int*   hist  = (int*)((char*)ebuf + (size_t)E * sizeof(unsigned));    // 128*NB_A
    int*   btot  = (int*)((char*)hist + (size_t)128 * NB_A * sizeof(int));// 128
    int*   bbase = (int*)((char*)btot + (size_t)128 * sizeof(int));       // 128
    int*   lock  = (int*)((char*)bbase + (size_t)128 * sizeof(int));      // 1
    unsigned short* WbfT = (unsigned short*)((char*)lock + 64);           // 16384 bf16

    hist_kernel<<<NB_A, 256, 0, stream>>>(edge_w, W, WbfT, hist, lock, E, nbuck, chunk);
    scanhist_kernel<<<nbuck, 1024, 0, stream>>>(hist, btot, bbase, off, lock, NB_A, nbuck, N, E);
    bucket_kernel<<<NB_A, 256, 0, stream>>>(edge_w, hist, bbase, ebuf, E, nbuck, chunk);
    csrgemm_kernel<<<nbuck + ntiles, 512, 0, stream>>>(ebuf, bbase, btot, adj, off, dis,
                                                       x, WbfT, hp, N, nbuck);

    int waves = (N + 1) / 2;                   // 2 nodes per wave
    gather_kernel<<<(waves + 3) / 4, 256, 0, stream>>>(hp, x, off, adj, dis, b, out, N);
}